// Round 1
// baseline (76.152 us; speedup 1.0000x reference)
//
#include <hip/hip_runtime.h>
#include <hip/hip_bf16.h>

// out[p] = sum_c (l[p,c] + g[p,c]) * u[c],  p in [0, B*H*W), C = 512 fp32.
// One wave (64 lanes) per pixel; lane i covers c in [i*8, i*8+8) via 2x float4.
// u preloaded to registers (reused across all pixels a wave processes).

__global__ __launch_bounds__(256) void pc_dot_kernel(
    const float4* __restrict__ l4,
    const float4* __restrict__ g4,
    const float4* __restrict__ u4,
    float* __restrict__ out,
    int npix)
{
    const int lane   = threadIdx.x & 63;
    const int wavesPerBlock = blockDim.x >> 6;
    const int wave   = blockIdx.x * wavesPerBlock + (threadIdx.x >> 6);
    const int nwaves = gridDim.x * wavesPerBlock;

    // u: 512 floats = 128 float4; lane i takes [2i, 2i+1]
    const float4 u0 = u4[lane * 2 + 0];
    const float4 u1 = u4[lane * 2 + 1];

    for (int p = wave; p < npix; p += nwaves) {
        const size_t base = (size_t)p * 128 + (size_t)(lane * 2);
        const float4 l0 = l4[base + 0];
        const float4 l1 = l4[base + 1];
        const float4 g0 = g4[base + 0];
        const float4 g1 = g4[base + 1];

        float s;
        s  = (l0.x + g0.x) * u0.x;
        s += (l0.y + g0.y) * u0.y;
        s += (l0.z + g0.z) * u0.z;
        s += (l0.w + g0.w) * u0.w;
        s += (l1.x + g1.x) * u1.x;
        s += (l1.y + g1.y) * u1.y;
        s += (l1.z + g1.z) * u1.z;
        s += (l1.w + g1.w) * u1.w;

        // 64-lane butterfly reduce
        #pragma unroll
        for (int m = 32; m >= 1; m >>= 1)
            s += __shfl_xor(s, m, 64);

        if (lane == 0) out[p] = s;
    }
}

extern "C" void kernel_launch(void* const* d_in, const int* in_sizes, int n_in,
                              void* d_out, int out_size, void* d_ws, size_t ws_size,
                              hipStream_t stream) {
    const float4* l4 = (const float4*)d_in[0];
    const float4* g4 = (const float4*)d_in[1];
    const float4* u4 = (const float4*)d_in[2];
    float* out = (float*)d_out;

    const int npix = out_size; // 32*56*56 = 100352

    const int block = 256;                 // 4 waves/block
    const int grid  = 2048;                // 8192 waves = full machine
    pc_dot_kernel<<<grid, block, 0, stream>>>(l4, g4, u4, out, npix);
}

// Round 2
// 75.176 us; speedup vs baseline: 1.0130x; 1.0130x over previous
//
#include <hip/hip_runtime.h>
#include <hip/hip_bf16.h>

// out[p] = sum_c (l[p,c] + g[p,c]) * u[c],  p in [0, B*H*W), C = 512 fp32.
// One wave (64 lanes) per pixel; lane i covers channels [8i, 8i+8) via 2x float4.
// u preloaded to registers. 2 pixels per loop iteration for MLP/ILP.
// Grid chosen so work divides exactly: 100352 px / 7168 waves = 14 px/wave,
// and 1792 blocks / 256 CUs = 7 blocks/CU exactly (no tail imbalance).

__global__ __launch_bounds__(256) void pc_dot_kernel(
    const float4* __restrict__ l4,
    const float4* __restrict__ g4,
    const float4* __restrict__ u4,
    float* __restrict__ out,
    int npix)
{
    const int lane   = threadIdx.x & 63;
    const int wavesPerBlock = blockDim.x >> 6;
    const int wave   = blockIdx.x * wavesPerBlock + (threadIdx.x >> 6);
    const int nwaves = gridDim.x * wavesPerBlock;

    // u: 512 floats = 128 float4; lane i takes [2i, 2i+1]
    const float4 u0 = u4[lane * 2 + 0];
    const float4 u1 = u4[lane * 2 + 1];

    int p0 = wave;
    // paired iterations: pixels p0 and p0+nwaves
    for (; p0 + nwaves < npix; p0 += 2 * nwaves) {
        const int p1 = p0 + nwaves;
        const size_t b0 = (size_t)p0 * 128 + (size_t)(lane * 2);
        const size_t b1 = (size_t)p1 * 128 + (size_t)(lane * 2);

        // issue all 8 loads up front
        const float4 la0 = l4[b0 + 0];
        const float4 la1 = l4[b0 + 1];
        const float4 ga0 = g4[b0 + 0];
        const float4 ga1 = g4[b0 + 1];
        const float4 lb0 = l4[b1 + 0];
        const float4 lb1 = l4[b1 + 1];
        const float4 gb0 = g4[b1 + 0];
        const float4 gb1 = g4[b1 + 1];

        float s0, s1;
        s0  = (la0.x + ga0.x) * u0.x;
        s0 += (la0.y + ga0.y) * u0.y;
        s0 += (la0.z + ga0.z) * u0.z;
        s0 += (la0.w + ga0.w) * u0.w;
        s0 += (la1.x + ga1.x) * u1.x;
        s0 += (la1.y + ga1.y) * u1.y;
        s0 += (la1.z + ga1.z) * u1.z;
        s0 += (la1.w + ga1.w) * u1.w;

        s1  = (lb0.x + gb0.x) * u0.x;
        s1 += (lb0.y + gb0.y) * u0.y;
        s1 += (lb0.z + gb0.z) * u0.z;
        s1 += (lb0.w + gb0.w) * u0.w;
        s1 += (lb1.x + gb1.x) * u1.x;
        s1 += (lb1.y + gb1.y) * u1.y;
        s1 += (lb1.z + gb1.z) * u1.z;
        s1 += (lb1.w + gb1.w) * u1.w;

        // two interleaved 64-lane butterfly reduces
        #pragma unroll
        for (int m = 32; m >= 1; m >>= 1) {
            s0 += __shfl_xor(s0, m, 64);
            s1 += __shfl_xor(s1, m, 64);
        }

        if (lane == 0) {
            out[p0] = s0;
            out[p1] = s1;
        }
    }
    // tail (at most one pixel per wave)
    if (p0 < npix) {
        const size_t b0 = (size_t)p0 * 128 + (size_t)(lane * 2);
        const float4 la0 = l4[b0 + 0];
        const float4 la1 = l4[b0 + 1];
        const float4 ga0 = g4[b0 + 0];
        const float4 ga1 = g4[b0 + 1];

        float s0;
        s0  = (la0.x + ga0.x) * u0.x;
        s0 += (la0.y + ga0.y) * u0.y;
        s0 += (la0.z + ga0.z) * u0.z;
        s0 += (la0.w + ga0.w) * u0.w;
        s0 += (la1.x + ga1.x) * u1.x;
        s0 += (la1.y + ga1.y) * u1.y;
        s0 += (la1.z + ga1.z) * u1.z;
        s0 += (la1.w + ga1.w) * u1.w;

        #pragma unroll
        for (int m = 32; m >= 1; m >>= 1)
            s0 += __shfl_xor(s0, m, 64);

        if (lane == 0) out[p0] = s0;
    }
}

extern "C" void kernel_launch(void* const* d_in, const int* in_sizes, int n_in,
                              void* d_out, int out_size, void* d_ws, size_t ws_size,
                              hipStream_t stream) {
    const float4* l4 = (const float4*)d_in[0];
    const float4* g4 = (const float4*)d_in[1];
    const float4* u4 = (const float4*)d_in[2];
    float* out = (float*)d_out;

    const int npix = out_size; // 32*56*56 = 100352

    // 1792 blocks x 4 waves = 7168 waves; 100352/7168 = 14 px/wave exactly;
    // 1792/256 CU = 7 blocks/CU exactly.
    const int block = 256;
    const int grid  = 1792;
    pc_dot_kernel<<<grid, block, 0, stream>>>(l4, g4, u4, out, npix);
}